// Round 1
// baseline (376.705 us; speedup 1.0000x reference)
//
#include <hip/hip_runtime.h>
#include <cstdint>

typedef unsigned short u16;
typedef __bf16 bf16x8 __attribute__((ext_vector_type(8)));
typedef float f32x4 __attribute__((ext_vector_type(4)));

#define B_   8
#define N_   8192
#define S_   2048
#define D1_  128
#define D2_  256
#define INCH 384
#define M_   (B_ * N_)   // 65536 rows total

__device__ __forceinline__ u16 f2bf(float f) {
  union { float f; unsigned u; } a; a.f = f;
  unsigned u = a.u;
  return (u16)((u + 0x7fffu + ((u >> 16) & 1u)) >> 16);  // RNE
}
__device__ __forceinline__ float bf2f(u16 h) {
  union { unsigned u; float f; } a; a.u = ((unsigned)h) << 16;
  return a.f;
}

__device__ __forceinline__ void async16(const void* g, void* l) {
  __builtin_amdgcn_global_load_lds((const __attribute__((address_space(1))) unsigned int*)g,
                                   (__attribute__((address_space(3))) unsigned int*)l,
                                   16, 0, 0);
}

// ---------------------------------------------------------------- 3-NN
// one thread per query point; xyz2[b] staged in LDS (24 KB)
__global__ __launch_bounds__(256) void knn_kernel(const float* __restrict__ xyz1,
                                                  const float* __restrict__ xyz2,
                                                  int* __restrict__ oidx,
                                                  float* __restrict__ owgt) {
  __shared__ float sp[S_ * 3];
  const int b = blockIdx.y;
  for (int i = threadIdx.x; i < S_ * 3; i += 256) sp[i] = xyz2[b * S_ * 3 + i];
  __syncthreads();
  const int n = blockIdx.x * 256 + threadIdx.x;
  const int p = b * N_ + n;
  const float px = xyz1[p * 3 + 0], py = xyz1[p * 3 + 1], pz = xyz1[p * 3 + 2];
  float d0 = 3e38f, d1 = 3e38f, d2 = 3e38f;
  int i0 = 0, i1 = 0, i2 = 0;
  for (int s = 0; s < S_; ++s) {
    float dx = px - sp[3 * s], dy = py - sp[3 * s + 1], dz = pz - sp[3 * s + 2];
    float d = dx * dx + dy * dy + dz * dz;
    if (d < d2) {                      // rare after warm-up: ~3 ln(S) updates
      if (d < d1) {
        d2 = d1; i2 = i1;
        if (d < d0) { d1 = d0; i1 = i0; d0 = d; i0 = s; }
        else        { d1 = d;  i1 = s; }
      } else { d2 = d; i2 = s; }
    }
  }
  d0 = fmaxf(d0, 1e-10f); d1 = fmaxf(d1, 1e-10f); d2 = fmaxf(d2, 1e-10f);
  float v0 = 1.f / d0, v1 = 1.f / d1, v2 = 1.f / d2;
  float inv = 1.f / (v0 + v1 + v2);
  oidx[p * 3 + 0] = i0; oidx[p * 3 + 1] = i1; oidx[p * 3 + 2] = i2;
  owgt[p * 3 + 0] = v0 * inv; owgt[p * 3 + 1] = v1 * inv; owgt[p * 3 + 2] = v2 * inv;
}

// ------------------------------------------- interpolate + concat -> bf16 xcat
// one wave per point: lanes cover channels
__global__ __launch_bounds__(256) void interp_kernel(const float* __restrict__ points1,
                                                     const float* __restrict__ points2,
                                                     const int* __restrict__ idx,
                                                     const float* __restrict__ wgt,
                                                     u16* __restrict__ xcat) {
  const int p = blockIdx.x * 4 + (threadIdx.x >> 6);
  const int l = threadIdx.x & 63;
  const int b = p >> 13;  // N_=8192
  const float* P1 = points1 + (size_t)p * D1_;
  u16* xr = xcat + (size_t)p * INCH;
  xr[l]      = f2bf(P1[l]);
  xr[l + 64] = f2bf(P1[l + 64]);
  const int i0 = idx[p * 3 + 0], i1 = idx[p * 3 + 1], i2 = idx[p * 3 + 2];
  const float w0 = wgt[p * 3 + 0], w1 = wgt[p * 3 + 1], w2 = wgt[p * 3 + 2];
  const float* Q0 = points2 + ((size_t)b * S_ + i0) * D2_;
  const float* Q1 = points2 + ((size_t)b * S_ + i1) * D2_;
  const float* Q2 = points2 + ((size_t)b * S_ + i2) * D2_;
#pragma unroll
  for (int j = 0; j < 4; ++j) {
    int c = l + j * 64;
    xr[D1_ + c] = f2bf(w0 * Q0[c] + w1 * Q1[c] + w2 * Q2[c]);
  }
}

// ---------------------------------------------------------------- weights->bf16
__global__ __launch_bounds__(256) void wconv_kernel(const float* __restrict__ w0,
                                                    const float* __restrict__ w1,
                                                    u16* __restrict__ w0b,
                                                    u16* __restrict__ w1b) {
  int i = blockIdx.x * 256 + threadIdx.x;
  if (i < 256 * INCH) w0b[i] = f2bf(w0[i]);
  if (i < 128 * 256)  w1b[i] = f2bf(w1[i]);
}

// ---------------------------------------------------------------- MFMA GEMM
// C[M,NT] = A[M,K] * W[NT,K]^T ; writes bf16 Y and per-channel sum/sumsq atomics.
// 128x128 tile, BK=64, 4 waves (2x2), global_load_lds w=16, XOR chunk swizzle.
template <int K, int NT>
__global__ __launch_bounds__(256, 2) void gemm_bn(const u16* __restrict__ A,
                                                  const u16* __restrict__ W,
                                                  u16* __restrict__ Y,
                                                  float* __restrict__ gsum,
                                                  float* __restrict__ gsq) {
  __shared__ u16 As[128 * 64];
  __shared__ u16 Ws[128 * 64];
  __shared__ float s_sum[128];
  __shared__ float s_sq[128];
  const int tid = threadIdx.x;
  const int lane = tid & 63, wid = tid >> 6;
  const int wr = wid >> 1, wc = wid & 1;
  const int brow = blockIdx.x * 128, bcol = blockIdx.y * 128;
  const int rr = tid >> 3, ss = tid & 7;   // staging: 8 lanes x 16B per row-64
  f32x4 acc[4][4] = {};

  for (int kt = 0; kt < K / 64; ++kt) {
    if (kt) __syncthreads();
#pragma unroll
    for (int it = 0; it < 4; ++it) {
      int row = it * 32 + rr;
      int ch = ss ^ (row & 7);           // inverse-swizzled global source chunk
      async16(&A[(size_t)(brow + row) * K + kt * 64 + ch * 8], &As[(it * 256 + tid) * 8]);
      async16(&W[(size_t)(bcol + row) * K + kt * 64 + ch * 8], &Ws[(it * 256 + tid) * 8]);
    }
    __syncthreads();
#pragma unroll
    for (int ks = 0; ks < 2; ++ks) {
      bf16x8 af[4], wf[4];
#pragma unroll
      for (int i = 0; i < 4; ++i) {
        int ra = wr * 64 + i * 16 + (lane & 15);
        int ca = ks * 4 + (lane >> 4);
        af[i] = *(const bf16x8*)&As[ra * 64 + ((ca ^ (ra & 7)) * 8)];
        int rw = wc * 64 + i * 16 + (lane & 15);
        wf[i] = *(const bf16x8*)&Ws[rw * 64 + ((ca ^ (rw & 7)) * 8)];
      }
#pragma unroll
      for (int mi = 0; mi < 4; ++mi)
#pragma unroll
        for (int ni = 0; ni < 4; ++ni)
          acc[mi][ni] = __builtin_amdgcn_mfma_f32_16x16x32_bf16(af[mi], wf[ni], acc[mi][ni], 0, 0, 0);
    }
  }

  // epilogue: store bf16 + block-level BN partial sums
  __syncthreads();
  if (tid < 128) { s_sum[tid] = 0.f; s_sq[tid] = 0.f; }
  __syncthreads();
#pragma unroll
  for (int ni = 0; ni < 4; ++ni) {
    int coll = wc * 64 + ni * 16 + (lane & 15);
    float ps = 0.f, pq = 0.f;
#pragma unroll
    for (int mi = 0; mi < 4; ++mi) {
      int rowl = wr * 64 + mi * 16 + ((lane >> 4) << 2);
#pragma unroll
      for (int q = 0; q < 4; ++q) {
        float v = acc[mi][ni][q];
        ps += v; pq += v * v;
        Y[(size_t)(brow + rowl + q) * NT + bcol + coll] = f2bf(v);
      }
    }
    atomicAdd(&s_sum[coll], ps);
    atomicAdd(&s_sq[coll], pq);
  }
  __syncthreads();
  if (tid < 128) {
    unsafeAtomicAdd(&gsum[bcol + tid], s_sum[tid]);
    unsafeAtomicAdd(&gsq[bcol + tid], s_sq[tid]);
  }
}

// ---------------------------------------------------------------- BN finalize
__global__ void bn_finalize(const float* __restrict__ gsum, const float* __restrict__ gsq,
                            const float* __restrict__ gamma, const float* __restrict__ beta,
                            float* __restrict__ scale, float* __restrict__ shift, int nch) {
  int c = blockIdx.x * blockDim.x + threadIdx.x;
  if (c >= nch) return;
  const float invn = 1.f / 65536.f;
  float mean = gsum[c] * invn;
  float var = gsq[c] * invn - mean * mean;   // biased, as reference
  float s = gamma[c] * rsqrtf(var + 1e-5f);
  scale[c] = s;
  shift[c] = beta[c] - mean * s;
}

// ------------------------------------------------- BN+ReLU in-place (bf16)
template <int CMASK>
__global__ __launch_bounds__(256) void bn_relu_inplace(u16* __restrict__ y,
                                                       const float* __restrict__ scale,
                                                       const float* __restrict__ shift) {
  const int idx = blockIdx.x * 256 + threadIdx.x;
  uint4 v = ((uint4*)y)[idx];
  const int c0 = (idx * 8) & CMASK;
  unsigned w[4] = {v.x, v.y, v.z, v.w};
#pragma unroll
  for (int j = 0; j < 4; ++j) {
    float lo = bf2f((u16)(w[j] & 0xffff));
    float hi = bf2f((u16)(w[j] >> 16));
    lo = fmaxf(fmaf(lo, scale[c0 + 2 * j], shift[c0 + 2 * j]), 0.f);
    hi = fmaxf(fmaf(hi, scale[c0 + 2 * j + 1], shift[c0 + 2 * j + 1]), 0.f);
    w[j] = (unsigned)f2bf(lo) | ((unsigned)f2bf(hi) << 16);
  }
  ((uint4*)y)[idx] = make_uint4(w[0], w[1], w[2], w[3]);
}

// ------------------------------------------------- BN+ReLU -> f32 output
__global__ __launch_bounds__(256) void bn_out_kernel(const u16* __restrict__ y,
                                                     const float* __restrict__ scale,
                                                     const float* __restrict__ shift,
                                                     float* __restrict__ out) {
  const int idx = blockIdx.x * 256 + threadIdx.x;
  uint4 v = ((const uint4*)y)[idx];
  const int c0 = (idx * 8) & 127;
  unsigned w[4] = {v.x, v.y, v.z, v.w};
  float o[8];
#pragma unroll
  for (int j = 0; j < 4; ++j) {
    o[2 * j]     = fmaxf(fmaf(bf2f((u16)(w[j] & 0xffff)), scale[c0 + 2 * j],     shift[c0 + 2 * j]),     0.f);
    o[2 * j + 1] = fmaxf(fmaf(bf2f((u16)(w[j] >> 16)),    scale[c0 + 2 * j + 1], shift[c0 + 2 * j + 1]), 0.f);
  }
  float4* op = (float4*)(out + (size_t)idx * 8);
  op[0] = make_float4(o[0], o[1], o[2], o[3]);
  op[1] = make_float4(o[4], o[5], o[6], o[7]);
}

extern "C" void kernel_launch(void* const* d_in, const int* in_sizes, int n_in,
                              void* d_out, int out_size, void* d_ws, size_t ws_size,
                              hipStream_t stream) {
  const float* xyz1    = (const float*)d_in[0];
  const float* xyz2    = (const float*)d_in[1];
  const float* points1 = (const float*)d_in[2];
  const float* points2 = (const float*)d_in[3];
  const float* w0      = (const float*)d_in[4];
  // b0 (d_in[5]) / b1 (d_in[9]) are mathematically cancelled by training-mode BN
  const float* gamma0  = (const float*)d_in[6];
  const float* beta0   = (const float*)d_in[7];
  const float* w1      = (const float*)d_in[8];
  const float* gamma1  = (const float*)d_in[10];
  const float* beta1   = (const float*)d_in[11];

  char* ws = (char*)d_ws;
  u16* xcat = (u16*)ws;  ws += (size_t)M_ * INCH * 2;   // 50.3 MB
  u16* y0   = (u16*)ws;  ws += (size_t)M_ * 256 * 2;    // 33.6 MB
  u16* y1   = (u16*)ws;  ws += (size_t)M_ * 128 * 2;    // 16.8 MB
  int*   kidx = (int*)ws;   ws += (size_t)M_ * 3 * 4;
  float* kwgt = (float*)ws; ws += (size_t)M_ * 3 * 4;
  u16* w0b = (u16*)ws;   ws += 256 * INCH * 2;
  u16* w1b = (u16*)ws;   ws += 128 * 256 * 2;
  float* stats = (float*)ws; ws += 768 * 4;  // sum0[256] sq0[256] sum1[128] sq1[128]
  float* sca   = (float*)ws; ws += 768 * 4;  // scale0 shift0 scale1 shift1

  float* sum0 = stats,       *sq0 = stats + 256;
  float* sum1 = stats + 512, *sq1 = stats + 640;
  float* scale0 = sca,       *shift0 = sca + 256;
  float* scale1 = sca + 512, *shift1 = sca + 640;

  hipMemsetAsync(stats, 0, 768 * 4, stream);  // replays accumulate otherwise

  wconv_kernel<<<384, 256, 0, stream>>>(w0, w1, w0b, w1b);
  knn_kernel<<<dim3(N_ / 256, B_), 256, 0, stream>>>(xyz1, xyz2, kidx, kwgt);
  interp_kernel<<<M_ / 4, 256, 0, stream>>>(points1, points2, kidx, kwgt, xcat);

  gemm_bn<INCH, 256><<<dim3(M_ / 128, 2), 256, 0, stream>>>(xcat, w0b, y0, sum0, sq0);
  bn_finalize<<<1, 256, 0, stream>>>(sum0, sq0, gamma0, beta0, scale0, shift0, 256);
  bn_relu_inplace<255><<<(M_ * 256 / 8) / 256, 256, 0, stream>>>(y0, scale0, shift0);

  gemm_bn<256, 128><<<dim3(M_ / 128, 1), 256, 0, stream>>>(y0, w1b, y1, sum1, sq1);
  bn_finalize<<<1, 256, 0, stream>>>(sum1, sq1, gamma1, beta1, scale1, shift1, 128);
  bn_out_kernel<<<(M_ * 128 / 8) / 256, 256, 0, stream>>>(y1, scale1, shift1, (float*)d_out);
}

// Round 2
// 340.655 us; speedup vs baseline: 1.1058x; 1.1058x over previous
//
#include <hip/hip_runtime.h>
#include <cstdint>

typedef unsigned short u16;
typedef __bf16 bf16x8 __attribute__((ext_vector_type(8)));
typedef float f32x4 __attribute__((ext_vector_type(4)));

#define B_   8
#define N_   8192
#define S_   2048
#define D1_  128
#define D2_  256
#define INCH 384
#define M_   (B_ * N_)   // 65536 rows total

__device__ __forceinline__ u16 f2bf(float f) {
  union { float f; unsigned u; } a; a.f = f;
  unsigned u = a.u;
  return (u16)((u + 0x7fffu + ((u >> 16) & 1u)) >> 16);  // RNE
}
__device__ __forceinline__ float bf2f(u16 h) {
  union { unsigned u; float f; } a; a.u = ((unsigned)h) << 16;
  return a.f;
}

__device__ __forceinline__ void async16(const void* g, void* l) {
  __builtin_amdgcn_global_load_lds((const __attribute__((address_space(1))) unsigned int*)g,
                                   (__attribute__((address_space(3))) unsigned int*)l,
                                   16, 0, 0);
}

__device__ __forceinline__ void top3_insert(float d, int s,
                                            float& d0, float& d1, float& d2,
                                            int& i0, int& i1, int& i2) {
  if (d < d2) {
    if (d < d1) {
      d2 = d1; i2 = i1;
      if (d < d0) { d1 = d0; i1 = i0; d0 = d; i0 = s; }
      else        { d1 = d;  i1 = s; }
    } else { d2 = d; i2 = s; }
  }
}

// ---------------------------------------------------------------- 3-NN
// 4 threads per query point (each scans 512 of S=2048), shuffle-merge top-3.
// SoA LDS with per-chunk pad (stride 516 floats -> chunk bases in distinct banks).
__global__ __launch_bounds__(256) void knn_kernel(const float* __restrict__ xyz1,
                                                  const float* __restrict__ xyz2,
                                                  int* __restrict__ oidx,
                                                  float* __restrict__ owgt) {
  __shared__ float spx[4 * 516], spy[4 * 516], spz[4 * 516];
  const int b = blockIdx.y;
#pragma unroll
  for (int k = 0; k < 8; ++k) {
    int s = threadIdx.x + k * 256;
    int c = s >> 9, sl = s & 511;
    const float* q = xyz2 + ((size_t)b * S_ + s) * 3;
    spx[c * 516 + sl] = q[0];
    spy[c * 516 + sl] = q[1];
    spz[c * 516 + sl] = q[2];
  }
  __syncthreads();
  const int t = threadIdx.x;
  const int pl = t >> 2;     // point within block [0,64)
  const int ck = t & 3;      // S-chunk [0,4)
  const int n = blockIdx.x * 64 + pl;
  const int p = b * N_ + n;
  const float px = xyz1[p * 3 + 0], py = xyz1[p * 3 + 1], pz = xyz1[p * 3 + 2];
  float d0 = 3e38f, d1 = 3e38f, d2 = 3e38f;
  int i0 = 0, i1 = 0, i2 = 0;
  const int base = ck * 516;
  const int soff = ck * 512;
  for (int s = 0; s < 512; s += 8) {
    float4 x0 = *(const float4*)&spx[base + s];
    float4 x1 = *(const float4*)&spx[base + s + 4];
    float4 y0 = *(const float4*)&spy[base + s];
    float4 y1 = *(const float4*)&spy[base + s + 4];
    float4 z0 = *(const float4*)&spz[base + s];
    float4 z1 = *(const float4*)&spz[base + s + 4];
    float xs[8] = {x0.x, x0.y, x0.z, x0.w, x1.x, x1.y, x1.z, x1.w};
    float ys[8] = {y0.x, y0.y, y0.z, y0.w, y1.x, y1.y, y1.z, y1.w};
    float zs[8] = {z0.x, z0.y, z0.z, z0.w, z1.x, z1.y, z1.z, z1.w};
#pragma unroll
    for (int j = 0; j < 8; ++j) {
      float dx = px - xs[j], dy = py - ys[j], dz = pz - zs[j];
      float d = dx * dx + dy * dy + dz * dz;
      top3_insert(d, soff + s + j, d0, d1, d2, i0, i1, i2);
    }
  }
  // merge the 4 chunk-local top-3 lists (lane-0-of-4 datapath keeps
  // lowest-chunk preference on exact ties via strict <)
#pragma unroll
  for (int m = 1; m <= 2; m <<= 1) {
    float e0 = __shfl_xor(d0, m), e1 = __shfl_xor(d1, m), e2 = __shfl_xor(d2, m);
    int j0 = __shfl_xor(i0, m), j1 = __shfl_xor(i1, m), j2 = __shfl_xor(i2, m);
    top3_insert(e0, j0, d0, d1, d2, i0, i1, i2);
    top3_insert(e1, j1, d0, d1, d2, i0, i1, i2);
    top3_insert(e2, j2, d0, d1, d2, i0, i1, i2);
  }
  if (ck == 0) {
    d0 = fmaxf(d0, 1e-10f); d1 = fmaxf(d1, 1e-10f); d2 = fmaxf(d2, 1e-10f);
    float v0 = 1.f / d0, v1 = 1.f / d1, v2 = 1.f / d2;
    float inv = 1.f / (v0 + v1 + v2);
    oidx[p * 3 + 0] = i0; oidx[p * 3 + 1] = i1; oidx[p * 3 + 2] = i2;
    owgt[p * 3 + 0] = v0 * inv; owgt[p * 3 + 1] = v1 * inv; owgt[p * 3 + 2] = v2 * inv;
  }
}

// ------------------------------------------- interpolate + concat -> bf16 xcat
// one wave per point: lanes cover channels
__global__ __launch_bounds__(256) void interp_kernel(const float* __restrict__ points1,
                                                     const float* __restrict__ points2,
                                                     const int* __restrict__ idx,
                                                     const float* __restrict__ wgt,
                                                     u16* __restrict__ xcat) {
  const int p = blockIdx.x * 4 + (threadIdx.x >> 6);
  const int l = threadIdx.x & 63;
  const int b = p >> 13;  // N_=8192
  const float* P1 = points1 + (size_t)p * D1_;
  u16* xr = xcat + (size_t)p * INCH;
  xr[l]      = f2bf(P1[l]);
  xr[l + 64] = f2bf(P1[l + 64]);
  const int i0 = idx[p * 3 + 0], i1 = idx[p * 3 + 1], i2 = idx[p * 3 + 2];
  const float w0 = wgt[p * 3 + 0], w1 = wgt[p * 3 + 1], w2 = wgt[p * 3 + 2];
  const float* Q0 = points2 + ((size_t)b * S_ + i0) * D2_;
  const float* Q1 = points2 + ((size_t)b * S_ + i1) * D2_;
  const float* Q2 = points2 + ((size_t)b * S_ + i2) * D2_;
#pragma unroll
  for (int j = 0; j < 4; ++j) {
    int c = l + j * 64;
    xr[D1_ + c] = f2bf(w0 * Q0[c] + w1 * Q1[c] + w2 * Q2[c]);
  }
}

// ---------------------------------------------------------------- weights->bf16
__global__ __launch_bounds__(256) void wconv_kernel(const float* __restrict__ w0,
                                                    const float* __restrict__ w1,
                                                    u16* __restrict__ w0b,
                                                    u16* __restrict__ w1b) {
  int i = blockIdx.x * 256 + threadIdx.x;
  if (i < 256 * INCH) w0b[i] = f2bf(w0[i]);
  if (i < 128 * 256)  w1b[i] = f2bf(w1[i]);
}

// ---------------------------------------------------------------- MFMA GEMM
// C[M,NT] = A[M,K] * W[NT,K]^T ; writes bf16 Y and per-channel sum/sumsq atomics.
// 128x128 tile, BK=64, 4 waves (2x2), global_load_lds w=16, XOR chunk swizzle.
template <int K, int NT>
__global__ __launch_bounds__(256, 2) void gemm_bn(const u16* __restrict__ A,
                                                  const u16* __restrict__ W,
                                                  u16* __restrict__ Y,
                                                  float* __restrict__ gsum,
                                                  float* __restrict__ gsq) {
  __shared__ u16 As[128 * 64];
  __shared__ u16 Ws[128 * 64];
  __shared__ float s_sum[128];
  __shared__ float s_sq[128];
  const int tid = threadIdx.x;
  const int lane = tid & 63, wid = tid >> 6;
  const int wr = wid >> 1, wc = wid & 1;
  const int brow = blockIdx.x * 128, bcol = blockIdx.y * 128;
  const int rr = tid >> 3, ss = tid & 7;   // staging: 8 lanes x 16B per row-64
  f32x4 acc[4][4] = {};

  for (int kt = 0; kt < K / 64; ++kt) {
    if (kt) __syncthreads();
#pragma unroll
    for (int it = 0; it < 4; ++it) {
      int row = it * 32 + rr;
      int ch = ss ^ (row & 7);           // inverse-swizzled global source chunk
      async16(&A[(size_t)(brow + row) * K + kt * 64 + ch * 8], &As[(it * 256 + tid) * 8]);
      async16(&W[(size_t)(bcol + row) * K + kt * 64 + ch * 8], &Ws[(it * 256 + tid) * 8]);
    }
    __syncthreads();
#pragma unroll
    for (int ks = 0; ks < 2; ++ks) {
      bf16x8 af[4], wf[4];
#pragma unroll
      for (int i = 0; i < 4; ++i) {
        int ra = wr * 64 + i * 16 + (lane & 15);
        int ca = ks * 4 + (lane >> 4);
        af[i] = *(const bf16x8*)&As[ra * 64 + ((ca ^ (ra & 7)) * 8)];
        int rw = wc * 64 + i * 16 + (lane & 15);
        wf[i] = *(const bf16x8*)&Ws[rw * 64 + ((ca ^ (rw & 7)) * 8)];
      }
#pragma unroll
      for (int mi = 0; mi < 4; ++mi)
#pragma unroll
        for (int ni = 0; ni < 4; ++ni)
          acc[mi][ni] = __builtin_amdgcn_mfma_f32_16x16x32_bf16(af[mi], wf[ni], acc[mi][ni], 0, 0, 0);
    }
  }

  // epilogue: store bf16 + block-level BN partial sums
  __syncthreads();
  if (tid < 128) { s_sum[tid] = 0.f; s_sq[tid] = 0.f; }
  __syncthreads();
#pragma unroll
  for (int ni = 0; ni < 4; ++ni) {
    int coll = wc * 64 + ni * 16 + (lane & 15);
    float ps = 0.f, pq = 0.f;
#pragma unroll
    for (int mi = 0; mi < 4; ++mi) {
      int rowl = wr * 64 + mi * 16 + ((lane >> 4) << 2);
#pragma unroll
      for (int q = 0; q < 4; ++q) {
        float v = acc[mi][ni][q];
        ps += v; pq += v * v;
        Y[(size_t)(brow + rowl + q) * NT + bcol + coll] = f2bf(v);
      }
    }
    atomicAdd(&s_sum[coll], ps);
    atomicAdd(&s_sq[coll], pq);
  }
  __syncthreads();
  if (tid < 128) {
    unsafeAtomicAdd(&gsum[bcol + tid], s_sum[tid]);
    unsafeAtomicAdd(&gsq[bcol + tid], s_sq[tid]);
  }
}

// ---------------------------------------------------------------- BN finalize
__global__ void bn_finalize(const float* __restrict__ gsum, const float* __restrict__ gsq,
                            const float* __restrict__ gamma, const float* __restrict__ beta,
                            float* __restrict__ scale, float* __restrict__ shift, int nch) {
  int c = blockIdx.x * blockDim.x + threadIdx.x;
  if (c >= nch) return;
  const float invn = 1.f / 65536.f;
  float mean = gsum[c] * invn;
  float var = gsq[c] * invn - mean * mean;   // biased, as reference
  float s = gamma[c] * rsqrtf(var + 1e-5f);
  scale[c] = s;
  shift[c] = beta[c] - mean * s;
}

// ------------------------------------------------- BN+ReLU in-place (bf16)
template <int CMASK>
__global__ __launch_bounds__(256) void bn_relu_inplace(u16* __restrict__ y,
                                                       const float* __restrict__ scale,
                                                       const float* __restrict__ shift) {
  const int idx = blockIdx.x * 256 + threadIdx.x;
  uint4 v = ((uint4*)y)[idx];
  const int c0 = (idx * 8) & CMASK;
  unsigned w[4] = {v.x, v.y, v.z, v.w};
#pragma unroll
  for (int j = 0; j < 4; ++j) {
    float lo = bf2f((u16)(w[j] & 0xffff));
    float hi = bf2f((u16)(w[j] >> 16));
    lo = fmaxf(fmaf(lo, scale[c0 + 2 * j], shift[c0 + 2 * j]), 0.f);
    hi = fmaxf(fmaf(hi, scale[c0 + 2 * j + 1], shift[c0 + 2 * j + 1]), 0.f);
    w[j] = (unsigned)f2bf(lo) | ((unsigned)f2bf(hi) << 16);
  }
  ((uint4*)y)[idx] = make_uint4(w[0], w[1], w[2], w[3]);
}

// ------------------------------------------------- BN+ReLU -> f32 output
__global__ __launch_bounds__(256) void bn_out_kernel(const u16* __restrict__ y,
                                                     const float* __restrict__ scale,
                                                     const float* __restrict__ shift,
                                                     float* __restrict__ out) {
  const int idx = blockIdx.x * 256 + threadIdx.x;
  uint4 v = ((const uint4*)y)[idx];
  const int c0 = (idx * 8) & 127;
  unsigned w[4] = {v.x, v.y, v.z, v.w};
  float o[8];
#pragma unroll
  for (int j = 0; j < 4; ++j) {
    o[2 * j]     = fmaxf(fmaf(bf2f((u16)(w[j] & 0xffff)), scale[c0 + 2 * j],     shift[c0 + 2 * j]),     0.f);
    o[2 * j + 1] = fmaxf(fmaf(bf2f((u16)(w[j] >> 16)),    scale[c0 + 2 * j + 1], shift[c0 + 2 * j + 1]), 0.f);
  }
  float4* op = (float4*)(out + (size_t)idx * 8);
  op[0] = make_float4(o[0], o[1], o[2], o[3]);
  op[1] = make_float4(o[4], o[5], o[6], o[7]);
}

extern "C" void kernel_launch(void* const* d_in, const int* in_sizes, int n_in,
                              void* d_out, int out_size, void* d_ws, size_t ws_size,
                              hipStream_t stream) {
  const float* xyz1    = (const float*)d_in[0];
  const float* xyz2    = (const float*)d_in[1];
  const float* points1 = (const float*)d_in[2];
  const float* points2 = (const float*)d_in[3];
  const float* w0      = (const float*)d_in[4];
  // b0 (d_in[5]) / b1 (d_in[9]) are mathematically cancelled by training-mode BN
  const float* gamma0  = (const float*)d_in[6];
  const float* beta0   = (const float*)d_in[7];
  const float* w1      = (const float*)d_in[8];
  const float* gamma1  = (const float*)d_in[10];
  const float* beta1   = (const float*)d_in[11];

  char* ws = (char*)d_ws;
  u16* xcat = (u16*)ws;  ws += (size_t)M_ * INCH * 2;   // 50.3 MB
  u16* y0   = (u16*)ws;  ws += (size_t)M_ * 256 * 2;    // 33.6 MB
  u16* y1   = (u16*)ws;  ws += (size_t)M_ * 128 * 2;    // 16.8 MB
  int*   kidx = (int*)ws;   ws += (size_t)M_ * 3 * 4;
  float* kwgt = (float*)ws; ws += (size_t)M_ * 3 * 4;
  u16* w0b = (u16*)ws;   ws += 256 * INCH * 2;
  u16* w1b = (u16*)ws;   ws += 128 * 256 * 2;
  float* stats = (float*)ws; ws += 768 * 4;  // sum0[256] sq0[256] sum1[128] sq1[128]
  float* sca   = (float*)ws; ws += 768 * 4;  // scale0 shift0 scale1 shift1

  float* sum0 = stats,       *sq0 = stats + 256;
  float* sum1 = stats + 512, *sq1 = stats + 640;
  float* scale0 = sca,       *shift0 = sca + 256;
  float* scale1 = sca + 512, *shift1 = sca + 640;

  hipMemsetAsync(stats, 0, 768 * 4, stream);  // replays accumulate otherwise

  wconv_kernel<<<384, 256, 0, stream>>>(w0, w1, w0b, w1b);
  knn_kernel<<<dim3(N_ / 64, B_), 256, 0, stream>>>(xyz1, xyz2, kidx, kwgt);
  interp_kernel<<<M_ / 4, 256, 0, stream>>>(points1, points2, kidx, kwgt, xcat);

  gemm_bn<INCH, 256><<<dim3(M_ / 128, 2), 256, 0, stream>>>(xcat, w0b, y0, sum0, sq0);
  bn_finalize<<<1, 256, 0, stream>>>(sum0, sq0, gamma0, beta0, scale0, shift0, 256);
  bn_relu_inplace<255><<<(M_ * 256 / 8) / 256, 256, 0, stream>>>(y0, scale0, shift0);

  gemm_bn<256, 128><<<dim3(M_ / 128, 1), 256, 0, stream>>>(y0, w1b, y1, sum1, sq1);
  bn_finalize<<<1, 256, 0, stream>>>(sum1, sq1, gamma1, beta1, scale1, shift1, 128);
  bn_out_kernel<<<(M_ * 128 / 8) / 256, 256, 0, stream>>>(y1, scale1, shift1, (float*)d_out);
}

// Round 3
// 210.151 us; speedup vs baseline: 1.7925x; 1.6210x over previous
//
#include <hip/hip_runtime.h>
#include <cstdint>

typedef unsigned short u16;
typedef __bf16 bf16x8 __attribute__((ext_vector_type(8)));
typedef float f32x4 __attribute__((ext_vector_type(4)));

#define B_   8
#define N_   8192
#define S_   2048
#define D1_  128
#define D2_  256
#define INCH 384
#define M_   (B_ * N_)   // 65536 rows total

__device__ __forceinline__ u16 f2bf(float f) {
  union { float f; unsigned u; } a; a.f = f;
  unsigned u = a.u;
  return (u16)((u + 0x7fffu + ((u >> 16) & 1u)) >> 16);  // RNE
}
__device__ __forceinline__ float bf2f(u16 h) {
  union { unsigned u; float f; } a; a.u = ((unsigned)h) << 16;
  return a.f;
}

__device__ __forceinline__ void async16(const void* g, void* l) {
  __builtin_amdgcn_global_load_lds((const __attribute__((address_space(1))) unsigned int*)g,
                                   (__attribute__((address_space(3))) unsigned int*)l,
                                   16, 0, 0);
}

// Branchless top-3 insert; exact same semantics as the nested strict-< cascade
// (lowest-index preference on ties). 11 VALU ops, no exec-mask traffic.
__device__ __forceinline__ void top3_bl(float d, int s,
                                        float& d0, float& d1, float& d2,
                                        int& i0, int& i1, int& i2) {
  const bool c0 = d < d0, c1 = d < d1, c2 = d < d2;
  const float n1 = __builtin_amdgcn_fmed3f(d, d0, d1);
  const float n2 = __builtin_amdgcn_fmed3f(d, d1, d2);
  i2 = c1 ? i1 : (c2 ? s : i2);   // reverse order: RHS uses old i1/i0
  i1 = c0 ? i0 : (c1 ? s : i1);
  i0 = c0 ? s : i0;
  d0 = fminf(d, d0);
  d1 = n1;
  d2 = n2;
}

// ---------------------------------------------------------------- 3-NN
// 8 chunks x 256 candidates; each thread serves 2 query points (Q=2) so each
// LDS candidate read is reused twice. Branchless inserts. Shuffle-merge the
// 8 chunk-local top-3 lists (xor 1,2,4; strict < keeps lowest-chunk on ties).
__global__ __launch_bounds__(256) void knn_kernel(const float* __restrict__ xyz1,
                                                  const float* __restrict__ xyz2,
                                                  int* __restrict__ oidx,
                                                  float* __restrict__ owgt) {
  __shared__ float spx[8 * 260], spy[8 * 260], spz[8 * 260];
  const int b = blockIdx.y;
#pragma unroll
  for (int k = 0; k < 8; ++k) {
    int s = threadIdx.x + k * 256;
    int c = s >> 8, sl = s & 255;
    const float* q = xyz2 + ((size_t)b * S_ + s) * 3;
    spx[c * 260 + sl] = q[0];
    spy[c * 260 + sl] = q[1];
    spz[c * 260 + sl] = q[2];
  }
  __syncthreads();
  const int t = threadIdx.x;
  const int pw = t >> 3;     // point-pair within block [0,32)
  const int ck = t & 7;      // S-chunk [0,8)
  const int n0 = blockIdx.x * 64 + pw * 2;
  const int p0 = b * N_ + n0;
  const int p1 = p0 + 1;
  const float ax = xyz1[p0 * 3 + 0], ay = xyz1[p0 * 3 + 1], az = xyz1[p0 * 3 + 2];
  const float bx = xyz1[p1 * 3 + 0], by = xyz1[p1 * 3 + 1], bz = xyz1[p1 * 3 + 2];
  float a0 = 3e38f, a1 = 3e38f, a2 = 3e38f;
  float b0 = 3e38f, b1 = 3e38f, b2 = 3e38f;
  int ai0 = 0, ai1 = 0, ai2 = 0;
  int bi0 = 0, bi1 = 0, bi2 = 0;
  const int base = ck * 260;
  const int soff = ck * 256;
  for (int s = 0; s < 256; s += 8) {
    float4 x0 = *(const float4*)&spx[base + s];
    float4 x1 = *(const float4*)&spx[base + s + 4];
    float4 y0 = *(const float4*)&spy[base + s];
    float4 y1 = *(const float4*)&spy[base + s + 4];
    float4 z0 = *(const float4*)&spz[base + s];
    float4 z1 = *(const float4*)&spz[base + s + 4];
    float xs[8] = {x0.x, x0.y, x0.z, x0.w, x1.x, x1.y, x1.z, x1.w};
    float ys[8] = {y0.x, y0.y, y0.z, y0.w, y1.x, y1.y, y1.z, y1.w};
    float zs[8] = {z0.x, z0.y, z0.z, z0.w, z1.x, z1.y, z1.z, z1.w};
#pragma unroll
    for (int j = 0; j < 8; ++j) {
      float dxa = ax - xs[j], dya = ay - ys[j], dza = az - zs[j];
      float da = dxa * dxa + dya * dya + dza * dza;
      top3_bl(da, soff + s + j, a0, a1, a2, ai0, ai1, ai2);
      float dxb = bx - xs[j], dyb = by - ys[j], dzb = bz - zs[j];
      float db = dxb * dxb + dyb * dyb + dzb * dzb;
      top3_bl(db, soff + s + j, b0, b1, b2, bi0, bi1, bi2);
    }
  }
  // merge 8 chunk-local lists (lane with lowest ck keeps ties via strict <)
#pragma unroll
  for (int m = 1; m <= 4; m <<= 1) {
    float e0 = __shfl_xor(a0, m), e1 = __shfl_xor(a1, m), e2 = __shfl_xor(a2, m);
    int j0 = __shfl_xor(ai0, m), j1 = __shfl_xor(ai1, m), j2 = __shfl_xor(ai2, m);
    top3_bl(e0, j0, a0, a1, a2, ai0, ai1, ai2);
    top3_bl(e1, j1, a0, a1, a2, ai0, ai1, ai2);
    top3_bl(e2, j2, a0, a1, a2, ai0, ai1, ai2);
    float f0 = __shfl_xor(b0, m), f1 = __shfl_xor(b1, m), f2 = __shfl_xor(b2, m);
    int k0 = __shfl_xor(bi0, m), k1 = __shfl_xor(bi1, m), k2 = __shfl_xor(bi2, m);
    top3_bl(f0, k0, b0, b1, b2, bi0, bi1, bi2);
    top3_bl(f1, k1, b0, b1, b2, bi0, bi1, bi2);
    top3_bl(f2, k2, b0, b1, b2, bi0, bi1, bi2);
  }
  if (ck == 0) {
    a0 = fmaxf(a0, 1e-10f); a1 = fmaxf(a1, 1e-10f); a2 = fmaxf(a2, 1e-10f);
    float v0 = 1.f / a0, v1 = 1.f / a1, v2 = 1.f / a2;
    float inv = 1.f / (v0 + v1 + v2);
    oidx[p0 * 3 + 0] = ai0; oidx[p0 * 3 + 1] = ai1; oidx[p0 * 3 + 2] = ai2;
    owgt[p0 * 3 + 0] = v0 * inv; owgt[p0 * 3 + 1] = v1 * inv; owgt[p0 * 3 + 2] = v2 * inv;
    b0 = fmaxf(b0, 1e-10f); b1 = fmaxf(b1, 1e-10f); b2 = fmaxf(b2, 1e-10f);
    float u0 = 1.f / b0, u1 = 1.f / b1, u2 = 1.f / b2;
    float uin = 1.f / (u0 + u1 + u2);
    oidx[p1 * 3 + 0] = bi0; oidx[p1 * 3 + 1] = bi1; oidx[p1 * 3 + 2] = bi2;
    owgt[p1 * 3 + 0] = u0 * uin; owgt[p1 * 3 + 1] = u1 * uin; owgt[p1 * 3 + 2] = u2 * uin;
  }
}

// ------------------------------------------- interpolate + concat -> bf16 xcat
// one wave per point: lanes cover channels
__global__ __launch_bounds__(256) void interp_kernel(const float* __restrict__ points1,
                                                     const float* __restrict__ points2,
                                                     const int* __restrict__ idx,
                                                     const float* __restrict__ wgt,
                                                     u16* __restrict__ xcat) {
  const int p = blockIdx.x * 4 + (threadIdx.x >> 6);
  const int l = threadIdx.x & 63;
  const int b = p >> 13;  // N_=8192
  const float* P1 = points1 + (size_t)p * D1_;
  u16* xr = xcat + (size_t)p * INCH;
  xr[l]      = f2bf(P1[l]);
  xr[l + 64] = f2bf(P1[l + 64]);
  const int i0 = idx[p * 3 + 0], i1 = idx[p * 3 + 1], i2 = idx[p * 3 + 2];
  const float w0 = wgt[p * 3 + 0], w1 = wgt[p * 3 + 1], w2 = wgt[p * 3 + 2];
  const float* Q0 = points2 + ((size_t)b * S_ + i0) * D2_;
  const float* Q1 = points2 + ((size_t)b * S_ + i1) * D2_;
  const float* Q2 = points2 + ((size_t)b * S_ + i2) * D2_;
#pragma unroll
  for (int j = 0; j < 4; ++j) {
    int c = l + j * 64;
    xr[D1_ + c] = f2bf(w0 * Q0[c] + w1 * Q1[c] + w2 * Q2[c]);
  }
}

// ---------------------------------------------------------------- weights->bf16
__global__ __launch_bounds__(256) void wconv_kernel(const float* __restrict__ w0,
                                                    const float* __restrict__ w1,
                                                    u16* __restrict__ w0b,
                                                    u16* __restrict__ w1b) {
  int i = blockIdx.x * 256 + threadIdx.x;
  if (i < 256 * INCH) w0b[i] = f2bf(w0[i]);
  if (i < 128 * 256)  w1b[i] = f2bf(w1[i]);
}

// ---------------------------------------------------------------- MFMA GEMM
// C[M,NT] = A[M,K] * W[NT,K]^T ; writes bf16 Y and per-channel sum/sumsq atomics.
// 128x128 tile, BK=64, 4 waves (2x2), global_load_lds w=16, XOR chunk swizzle.
template <int K, int NT>
__global__ __launch_bounds__(256, 2) void gemm_bn(const u16* __restrict__ A,
                                                  const u16* __restrict__ W,
                                                  u16* __restrict__ Y,
                                                  float* __restrict__ gsum,
                                                  float* __restrict__ gsq) {
  __shared__ u16 As[128 * 64];
  __shared__ u16 Ws[128 * 64];
  __shared__ float s_sum[128];
  __shared__ float s_sq[128];
  const int tid = threadIdx.x;
  const int lane = tid & 63, wid = tid >> 6;
  const int wr = wid >> 1, wc = wid & 1;
  const int brow = blockIdx.x * 128, bcol = blockIdx.y * 128;
  const int rr = tid >> 3, ss = tid & 7;   // staging: 8 lanes x 16B per row-64
  f32x4 acc[4][4] = {};

  for (int kt = 0; kt < K / 64; ++kt) {
    if (kt) __syncthreads();
#pragma unroll
    for (int it = 0; it < 4; ++it) {
      int row = it * 32 + rr;
      int ch = ss ^ (row & 7);           // inverse-swizzled global source chunk
      async16(&A[(size_t)(brow + row) * K + kt * 64 + ch * 8], &As[(it * 256 + tid) * 8]);
      async16(&W[(size_t)(bcol + row) * K + kt * 64 + ch * 8], &Ws[(it * 256 + tid) * 8]);
    }
    __syncthreads();
#pragma unroll
    for (int ks = 0; ks < 2; ++ks) {
      bf16x8 af[4], wf[4];
#pragma unroll
      for (int i = 0; i < 4; ++i) {
        int ra = wr * 64 + i * 16 + (lane & 15);
        int ca = ks * 4 + (lane >> 4);
        af[i] = *(const bf16x8*)&As[ra * 64 + ((ca ^ (ra & 7)) * 8)];
        int rw = wc * 64 + i * 16 + (lane & 15);
        wf[i] = *(const bf16x8*)&Ws[rw * 64 + ((ca ^ (rw & 7)) * 8)];
      }
#pragma unroll
      for (int mi = 0; mi < 4; ++mi)
#pragma unroll
        for (int ni = 0; ni < 4; ++ni)
          acc[mi][ni] = __builtin_amdgcn_mfma_f32_16x16x32_bf16(af[mi], wf[ni], acc[mi][ni], 0, 0, 0);
    }
  }

  // epilogue: store bf16 + block-level BN partial sums
  __syncthreads();
  if (tid < 128) { s_sum[tid] = 0.f; s_sq[tid] = 0.f; }
  __syncthreads();
#pragma unroll
  for (int ni = 0; ni < 4; ++ni) {
    int coll = wc * 64 + ni * 16 + (lane & 15);
    float ps = 0.f, pq = 0.f;
#pragma unroll
    for (int mi = 0; mi < 4; ++mi) {
      int rowl = wr * 64 + mi * 16 + ((lane >> 4) << 2);
#pragma unroll
      for (int q = 0; q < 4; ++q) {
        float v = acc[mi][ni][q];
        ps += v; pq += v * v;
        Y[(size_t)(brow + rowl + q) * NT + bcol + coll] = f2bf(v);
      }
    }
    atomicAdd(&s_sum[coll], ps);
    atomicAdd(&s_sq[coll], pq);
  }
  __syncthreads();
  if (tid < 128) {
    unsafeAtomicAdd(&gsum[bcol + tid], s_sum[tid]);
    unsafeAtomicAdd(&gsq[bcol + tid], s_sq[tid]);
  }
}

// ---------------------------------------------------------------- BN finalize
__global__ void bn_finalize(const float* __restrict__ gsum, const float* __restrict__ gsq,
                            const float* __restrict__ gamma, const float* __restrict__ beta,
                            float* __restrict__ scale, float* __restrict__ shift, int nch) {
  int c = blockIdx.x * blockDim.x + threadIdx.x;
  if (c >= nch) return;
  const float invn = 1.f / 65536.f;
  float mean = gsum[c] * invn;
  float var = gsq[c] * invn - mean * mean;   // biased, as reference
  float s = gamma[c] * rsqrtf(var + 1e-5f);
  scale[c] = s;
  shift[c] = beta[c] - mean * s;
}

// ------------------------------------------------- BN+ReLU in-place (bf16)
template <int CMASK>
__global__ __launch_bounds__(256) void bn_relu_inplace(u16* __restrict__ y,
                                                       const float* __restrict__ scale,
                                                       const float* __restrict__ shift) {
  const int idx = blockIdx.x * 256 + threadIdx.x;
  uint4 v = ((uint4*)y)[idx];
  const int c0 = (idx * 8) & CMASK;
  unsigned w[4] = {v.x, v.y, v.z, v.w};
#pragma unroll
  for (int j = 0; j < 4; ++j) {
    float lo = bf2f((u16)(w[j] & 0xffff));
    float hi = bf2f((u16)(w[j] >> 16));
    lo = fmaxf(fmaf(lo, scale[c0 + 2 * j], shift[c0 + 2 * j]), 0.f);
    hi = fmaxf(fmaf(hi, scale[c0 + 2 * j + 1], shift[c0 + 2 * j + 1]), 0.f);
    w[j] = (unsigned)f2bf(lo) | ((unsigned)f2bf(hi) << 16);
  }
  ((uint4*)y)[idx] = make_uint4(w[0], w[1], w[2], w[3]);
}

// ------------------------------------------------- BN+ReLU -> f32 output
__global__ __launch_bounds__(256) void bn_out_kernel(const u16* __restrict__ y,
                                                     const float* __restrict__ scale,
                                                     const float* __restrict__ shift,
                                                     float* __restrict__ out) {
  const int idx = blockIdx.x * 256 + threadIdx.x;
  uint4 v = ((const uint4*)y)[idx];
  const int c0 = (idx * 8) & 127;
  unsigned w[4] = {v.x, v.y, v.z, v.w};
  float o[8];
#pragma unroll
  for (int j = 0; j < 4; ++j) {
    o[2 * j]     = fmaxf(fmaf(bf2f((u16)(w[j] & 0xffff)), scale[c0 + 2 * j],     shift[c0 + 2 * j]),     0.f);
    o[2 * j + 1] = fmaxf(fmaf(bf2f((u16)(w[j] >> 16)),    scale[c0 + 2 * j + 1], shift[c0 + 2 * j + 1]), 0.f);
  }
  float4* op = (float4*)(out + (size_t)idx * 8);
  op[0] = make_float4(o[0], o[1], o[2], o[3]);
  op[1] = make_float4(o[4], o[5], o[6], o[7]);
}

extern "C" void kernel_launch(void* const* d_in, const int* in_sizes, int n_in,
                              void* d_out, int out_size, void* d_ws, size_t ws_size,
                              hipStream_t stream) {
  const float* xyz1    = (const float*)d_in[0];
  const float* xyz2    = (const float*)d_in[1];
  const float* points1 = (const float*)d_in[2];
  const float* points2 = (const float*)d_in[3];
  const float* w0      = (const float*)d_in[4];
  // b0 (d_in[5]) / b1 (d_in[9]) are mathematically cancelled by training-mode BN
  const float* gamma0  = (const float*)d_in[6];
  const float* beta0   = (const float*)d_in[7];
  const float* w1      = (const float*)d_in[8];
  const float* gamma1  = (const float*)d_in[10];
  const float* beta1   = (const float*)d_in[11];

  char* ws = (char*)d_ws;
  u16* xcat = (u16*)ws;  ws += (size_t)M_ * INCH * 2;   // 50.3 MB
  u16* y0   = (u16*)ws;  ws += (size_t)M_ * 256 * 2;    // 33.6 MB
  u16* y1   = (u16*)ws;  ws += (size_t)M_ * 128 * 2;    // 16.8 MB
  int*   kidx = (int*)ws;   ws += (size_t)M_ * 3 * 4;
  float* kwgt = (float*)ws; ws += (size_t)M_ * 3 * 4;
  u16* w0b = (u16*)ws;   ws += 256 * INCH * 2;
  u16* w1b = (u16*)ws;   ws += 128 * 256 * 2;
  float* stats = (float*)ws; ws += 768 * 4;  // sum0[256] sq0[256] sum1[128] sq1[128]
  float* sca   = (float*)ws; ws += 768 * 4;  // scale0 shift0 scale1 shift1

  float* sum0 = stats,       *sq0 = stats + 256;
  float* sum1 = stats + 512, *sq1 = stats + 640;
  float* scale0 = sca,       *shift0 = sca + 256;
  float* scale1 = sca + 512, *shift1 = sca + 640;

  hipMemsetAsync(stats, 0, 768 * 4, stream);  // replays accumulate otherwise

  wconv_kernel<<<384, 256, 0, stream>>>(w0, w1, w0b, w1b);
  knn_kernel<<<dim3(N_ / 64, B_), 256, 0, stream>>>(xyz1, xyz2, kidx, kwgt);
  interp_kernel<<<M_ / 4, 256, 0, stream>>>(points1, points2, kidx, kwgt, xcat);

  gemm_bn<INCH, 256><<<dim3(M_ / 128, 2), 256, 0, stream>>>(xcat, w0b, y0, sum0, sq0);
  bn_finalize<<<1, 256, 0, stream>>>(sum0, sq0, gamma0, beta0, scale0, shift0, 256);
  bn_relu_inplace<255><<<(M_ * 256 / 8) / 256, 256, 0, stream>>>(y0, scale0, shift0);

  gemm_bn<256, 128><<<dim3(M_ / 128, 1), 256, 0, stream>>>(y0, w1b, y1, sum1, sq1);
  bn_finalize<<<1, 256, 0, stream>>>(sum1, sq1, gamma1, beta1, scale1, shift1, 128);
  bn_out_kernel<<<(M_ * 128 / 8) / 256, 256, 0, stream>>>(y1, scale1, shift1, (float*)d_out);
}